// Round 5
// baseline (2010.349 us; speedup 1.0000x reference)
//
#include <hip/hip_runtime.h>
#include <math.h>

// Problem dims (fixed)
#define NOTES 78
#define IN_DIM 80
#define T_HID 64
#define N_HID 2
#define BATCH 64
#define TLEN 128
#define NSEQ (BATCH * NOTES)          // 4992 time-LSTM sequences
#define NBT  (BATCH * TLEN)           // 8192 note-LSTM sequences
#define NROWS (NSEQ * TLEN)           // 638976 (seq,t) rows

#define GXN_BYTES ((size_t)NOTES * NBT * 8 * 4)            // 20,447,232
#define GX_BYTES  ((size_t)NROWS * 256 * 4)                // 654,311,424
#define WS_NEED   (GXN_BYTES + GX_BYTES)

__device__ __forceinline__ float sigf(float x) { return 1.0f / (1.0f + expf(-x)); }
__device__ __forceinline__ float rdl(float v, int k) {
    return __int_as_float(__builtin_amdgcn_readlane(__float_as_int(v), k));
}

// ---------------------------------------------------------------------------
// Kernel 1: gx GEMM v2.  R9: R8's version was LDS-bound (16 fma per ds_read,
// 500us floor).  Fix: gate dim is WAVE-UNIFORM -> weights come from SGPRs
// (readfirstlane-hoisted scalar loads; v_fmac with SGPR operand = 1 inst/MAC,
// zero LDS for B), and x is read 1x b128 per 4k per 8 gates = 32 fma/read.
// Block: 256 thr, 64 rows, all 256 gates via 8 groups/wave. LDS 21 KB.
// ---------------------------------------------------------------------------
#define GR 64
__global__ __launch_bounds__(256, 4)
void gx_gemm2(const float* __restrict__ x,      // [NROWS][80]
              const float* __restrict__ w_ih,   // [256][80]
              const float* __restrict__ b_ih,
              const float* __restrict__ b_hh,
              float* __restrict__ gx) {         // [NROWS][256]
    __shared__ float xs[GR][84];   // pad 84: lane-stride mod 32 = 20 -> even bank spread

    const int tid = threadIdx.x;
    const size_t row0 = (size_t)blockIdx.x * GR;

    // stage x: 64 rows x 80 f = 1280 float4; coalesced read, strided LDS write
    {
        const float4* src = (const float4*)(x + row0 * IN_DIM);
#pragma unroll
        for (int j = 0; j < 5; j++) {
            const int i4 = tid + 256 * j;       // 0..1279
            const int r = i4 / 20, c4 = i4 % 20;
            const float4 v = src[i4];
            *(float4*)&xs[r][c4 * 4] = v;
        }
    }
    __syncthreads();

    const int lane = tid & 63;
    const int wvu = __builtin_amdgcn_readfirstlane(tid >> 6);   // uniform wave id
    const size_t row = row0 + lane;
    float* orow = gx + row * 256;

    for (int grp = 0; grp < 8; grp++) {
        const int g0 = (grp * 4 + wvu) * 8;     // uniform gate base
        float acc[8];
#pragma unroll
        for (int j = 0; j < 8; j++) acc[j] = 0.0f;

#pragma unroll 2
        for (int kc = 0; kc < 10; kc++) {       // k in chunks of 8
            float xv[8];
            *(float4*)&xv[0] = *(const float4*)&xs[lane][kc * 8];
            *(float4*)&xv[4] = *(const float4*)&xs[lane][kc * 8 + 4];
#pragma unroll
            for (int j = 0; j < 8; j++) {
                const float* wr = w_ih + (size_t)(g0 + j) * IN_DIM + kc * 8;
#pragma unroll
                for (int k = 0; k < 8; k++)
                    acc[j] = fmaf(wr[k], xv[k], acc[j]);   // SGPR weight operand
            }
        }
#pragma unroll
        for (int j = 0; j < 8; j++) acc[j] += b_ih[g0 + j] + b_hh[g0 + j];
        *(float4*)&orow[g0]     = make_float4(acc[0], acc[1], acc[2], acc[3]);
        *(float4*)&orow[g0 + 4] = make_float4(acc[4], acc[5], acc[6], acc[7]);
    }
}

// ---------------------------------------------------------------------------
// Kernel 2: h-recurrence v2.  R9: R8 was LDS-bound (64 shared-weight reads
// per wave-step serving ONE sequence -> 800us of LDS pipe).  Fix: 5 seqs per
// wave (reads are amortized 5x; fma is the useful work and now dominates).
// Grid 250 blocks = 1 block/CU, 1 wave/SIMD -> no block quantization
// imbalance; LDS demand/CU (164us) hides under VALU (~195us).
// __launch_bounds__(256,1): no VGPR cap -> no demotion games (R4/R5 lesson).
// ---------------------------------------------------------------------------
#define SPW 5                          // seqs per wave
#define SPB (4 * SPW)                  // 20 seqs per block
#define RECBLK ((NSEQ + SPB - 1) / SPB)  // 250
__global__ __launch_bounds__(256, 1)
void rec_h2(const float* __restrict__ gx,      // [NSEQ][TLEN][256]
            const float* __restrict__ w_hh,    // [256][64]
            const float* __restrict__ w_ih_n,  // [8][64]
            const float* __restrict__ b_ih_n,
            const float* __restrict__ b_hh_n,
            float* __restrict__ gxn) {         // [NOTES][NBT][8]
    __shared__ float4 wT4[16][256];    // 64 KB: wT4[k4][g] = w_hh[g][4k4..+3]

    const int tid = threadIdx.x;
    const int lane = tid & 63;
    const int w = tid >> 6;
    const int sb = blockIdx.x * SPB + w * SPW;

#pragma unroll
    for (int j = 0; j < 16; j++)
        wT4[j][tid] = *(const float4*)(w_hh + (size_t)tid * T_HID + 4 * j);
    __syncthreads();

    // gxn projection identity
    const int nj = lane >> 3;
    const int kk = (lane & 7) << 3;
    float wn[8];
#pragma unroll
    for (int i = 0; i < 8; i++) wn[i] = w_ih_n[nj * T_HID + kk + i];
    const float nbias = b_ih_n[nj] + b_hh_n[nj];

    const float* gp[SPW];
    float* gout[SPW];
    bool valid[SPW];
#pragma unroll
    for (int s = 0; s < SPW; s++) {
        const int sq = sb + s;
        valid[s] = (sq < NSEQ);
        const int sqc = valid[s] ? sq : 0;
        const int nb = sqc / NOTES, nn = sqc % NOTES;
        gout[s] = gxn + ((size_t)nn * NBT + (size_t)nb * TLEN) * 8 + nj;
        gp[s] = gx + (size_t)sqc * TLEN * 256 + lane;
    }
    float h[SPW], c[SPW];
#pragma unroll
    for (int s = 0; s < SPW; s++) { h[s] = 0.0f; c[s] = 0.0f; }

    for (int t = 0; t < TLEN; t++) {
        // gate pre-activations for unit=lane (issued early, used after MAC)
        float q0[SPW], q1[SPW], q2[SPW], q3[SPW];
#pragma unroll
        for (int s = 0; s < SPW; s++) {
            q0[s] = gp[s][0]; q1[s] = gp[s][64];
            q2[s] = gp[s][128]; q3[s] = gp[s][192];
            gp[s] += 256;
        }

        float a0[SPW], a1[SPW], a2[SPW], a3[SPW];
#pragma unroll
        for (int s = 0; s < SPW; s++) { a0[s]=0.f; a1[s]=0.f; a2[s]=0.f; a3[s]=0.f; }

#pragma unroll
        for (int k4 = 0; k4 < 16; k4++) {
            const float4 w0 = wT4[k4][lane];          // shared across 5 seqs
            const float4 w1 = wT4[k4][64 + lane];
            const float4 w2 = wT4[k4][128 + lane];
            const float4 w3 = wT4[k4][192 + lane];
#pragma unroll
            for (int s = 0; s < SPW; s++) {
                const float r0 = rdl(h[s], 4 * k4 + 0);
                const float r1 = rdl(h[s], 4 * k4 + 1);
                const float r2 = rdl(h[s], 4 * k4 + 2);
                const float r3 = rdl(h[s], 4 * k4 + 3);
                a0[s] = fmaf(w0.x, r0, a0[s]); a0[s] = fmaf(w0.y, r1, a0[s]);
                a0[s] = fmaf(w0.z, r2, a0[s]); a0[s] = fmaf(w0.w, r3, a0[s]);
                a1[s] = fmaf(w1.x, r0, a1[s]); a1[s] = fmaf(w1.y, r1, a1[s]);
                a1[s] = fmaf(w1.z, r2, a1[s]); a1[s] = fmaf(w1.w, r3, a1[s]);
                a2[s] = fmaf(w2.x, r0, a2[s]); a2[s] = fmaf(w2.y, r1, a2[s]);
                a2[s] = fmaf(w2.z, r2, a2[s]); a2[s] = fmaf(w2.w, r3, a2[s]);
                a3[s] = fmaf(w3.x, r0, a3[s]); a3[s] = fmaf(w3.y, r1, a3[s]);
                a3[s] = fmaf(w3.z, r2, a3[s]); a3[s] = fmaf(w3.w, r3, a3[s]);
            }
        }

#pragma unroll
        for (int s = 0; s < SPW; s++) {
            const float ip = q0[s] + a0[s];
            const float fp = q1[s] + a1[s];
            const float gg = q2[s] + a2[s];
            const float op = q3[s] + a3[s];
            c[s] = sigf(fp) * c[s] + sigf(ip) * tanhf(gg);
            h[s] = sigf(op) * tanhf(c[s]);

            // note-input projection of h_t: 8 outs, 8-way k-split, shfl gather
            float p = 0.0f;
#pragma unroll
            for (int i = 0; i < 8; i++) p = fmaf(wn[i], __shfl(h[s], kk + i), p);
            p += __shfl_xor(p, 1);
            p += __shfl_xor(p, 2);
            p += __shfl_xor(p, 4);
            if (valid[s] && (lane & 7) == 0) gout[s][(size_t)t * 8] = p + nbias;
        }
    }
}

// ---------------------------------------------------------------------------
// Kernel 3: note-LSTM scan over 78 notes, fresh zero state per (b,t).
// ---------------------------------------------------------------------------
__global__ __launch_bounds__(64)
void note_scan_kernel(const float* __restrict__ gxn,
                      const float* __restrict__ w_hh_n,
                      float* __restrict__ out) {
    const int bt = blockIdx.x * 64 + threadIdx.x;         // < 8192
    float wh[16];
#pragma unroll
    for (int i = 0; i < 16; i++) wh[i] = w_hh_n[i];       // [8][2] row-major
    float h0 = 0.f, h1 = 0.f, c0 = 0.f, c1 = 0.f;

    const float4* gp = (const float4*)gxn;                // f4 index = (n*NBT+bt)*2
    float4* op = (float4*)(out + (size_t)bt * (NOTES * N_HID));

    size_t idx = (size_t)bt * 2;
    float4 ga = gp[idx], gb = gp[idx + 1];
    for (int n0 = 0; n0 < NOTES; n0 += 2) {
        float r[4];
#pragma unroll
        for (int u = 0; u < 2; u++) {
            const int n = n0 + u;
            float4 na, nb2;
            if (n + 1 < NOTES) {
                const size_t nidx = ((size_t)(n + 1) * NBT + bt) * 2;
                na  = gp[nidx];
                nb2 = gp[nidx + 1];
            }
            const float i0 = ga.x + wh[0]  * h0 + wh[1]  * h1;
            const float i1 = ga.y + wh[2]  * h0 + wh[3]  * h1;
            const float f0 = ga.z + wh[4]  * h0 + wh[5]  * h1;
            const float f1 = ga.w + wh[6]  * h0 + wh[7]  * h1;
            const float g0 = gb.x + wh[8]  * h0 + wh[9]  * h1;
            const float g1 = gb.y + wh[10] * h0 + wh[11] * h1;
            const float o0 = gb.z + wh[12] * h0 + wh[13] * h1;
            const float o1 = gb.w + wh[14] * h0 + wh[15] * h1;
            c0 = sigf(f0) * c0 + sigf(i0) * tanhf(g0);
            c1 = sigf(f1) * c1 + sigf(i1) * tanhf(g1);
            h0 = sigf(o0) * tanhf(c0);
            h1 = sigf(o1) * tanhf(c1);
            r[2 * u + 0] = (h0 > 0.5f) ? 1.0f : 0.0f;
            r[2 * u + 1] = (h1 > 0.5f) ? 1.0f : 0.0f;
            ga = na; gb = nb2;
        }
        op[n0 >> 1] = make_float4(r[0], r[1], r[2], r[3]);
    }
}

// ---------------------------------------------------------------------------
// Fallback path (if workspace too small for gx): R5 fused kernel (1160 us).
// ---------------------------------------------------------------------------
#define SB 4
__global__ __launch_bounds__(512, 4)
void time_lstm_fused_fb(const float* __restrict__ x,
                        const float* __restrict__ w_ih,
                        const float* __restrict__ w_hh,
                        const float* __restrict__ b_ih,
                        const float* __restrict__ b_hh,
                        const float* __restrict__ w_ih_n,
                        const float* __restrict__ b_ih_n,
                        const float* __restrict__ b_hh_n,
                        float* __restrict__ gxn) {
    __shared__ float hbuf[SB][T_HID];
    __shared__ float Gx[2][SB][256];
    __shared__ float Gh[2][SB][256];

    const int tid  = threadIdx.x;
    const int s0   = blockIdx.x * SB;
    const int wid  = tid >> 6;
    const int lane = tid & 63;
    const bool isx = (wid < 4);
    const int lw   = isx ? wid : (wid - 4);
    const int kh   = lw >> 1;
    const int gh   = lw & 1;
    const int g0   = (gh << 7) | (2 * lane);

    float4 wA[10], wB[10];
    float biasA = 0.0f, biasB = 0.0f;
    if (isx) {
        const float4* pA = (const float4*)(w_ih + (size_t)g0 * IN_DIM + 40 * kh);
        const float4* pB = (const float4*)(w_ih + (size_t)(g0 + 1) * IN_DIM + 40 * kh);
#pragma unroll
        for (int j = 0; j < 10; j++) { wA[j] = pA[j]; wB[j] = pB[j]; }
        if (kh == 0) {
            biasA = b_ih[g0] + b_hh[g0];
            biasB = b_ih[g0 + 1] + b_hh[g0 + 1];
        }
    } else {
        const float4* pA = (const float4*)(w_hh + (size_t)g0 * T_HID + 32 * kh);
        const float4* pB = (const float4*)(w_hh + (size_t)(g0 + 1) * T_HID + 32 * kh);
#pragma unroll
        for (int j = 0; j < 8; j++) { wA[j] = pA[j]; wB[j] = pB[j]; }
    }

    const float* xr[SB];
#pragma unroll
    for (int s = 0; s < SB; s++) xr[s] = x + (size_t)(s0 + s) * TLEN * IN_DIM;

    const int ol = 40 * kh + (lane < 39 ? lane : 39);

    float xa[SB], xna[SB];
    if (isx) {
#pragma unroll
        for (int s = 0; s < SB; s++) xa[s] = xr[s][ol];
    }

    float cst = 0.0f;
    const int hol = (kh << 5) | (lane & 31);
    const int nj = (lane >> 3) & 7;
    const int nk = lane & 7;
    float wn[8];
    float nbias = 0.0f;
    float* gout = gxn;
    if (!isx) {
#pragma unroll
        for (int i = 0; i < 8; i++) wn[i] = w_ih_n[nj * 64 + nk * 8 + i];
        nbias = b_ih_n[nj] + b_hh_n[nj];
        const int sglb = s0 + lw;
        const int nb = sglb / NOTES, nn = sglb % NOTES;
        gout = gxn + ((size_t)nn * NBT + (size_t)nb * TLEN) * 8 + nj;
    }

    if (tid < SB * T_HID) hbuf[tid >> 6][tid & 63] = 0.0f;
    __syncthreads();

    for (int t = 0; t < TLEN; t++) {
        if (isx) {
            if (t + 1 < TLEN) {
#pragma unroll
                for (int s = 0; s < SB; s++) xna[s] = xr[s][(t + 1) * IN_DIM + ol];
            }
            float aA[SB], aB[SB];
#pragma unroll
            for (int s = 0; s < SB; s++) { aA[s] = biasA; aB[s] = biasB; }
#pragma unroll
            for (int k4 = 0; k4 < 10; k4++) {
                const float4 vA = wA[k4], vB = wB[k4];
#pragma unroll
                for (int s = 0; s < SB; s++) {
                    const float r0 = rdl(xa[s], 4 * k4 + 0);
                    const float r1 = rdl(xa[s], 4 * k4 + 1);
                    const float r2 = rdl(xa[s], 4 * k4 + 2);
                    const float r3 = rdl(xa[s], 4 * k4 + 3);
                    aA[s] = fmaf(vA.x, r0, aA[s]);  aB[s] = fmaf(vB.x, r0, aB[s]);
                    aA[s] = fmaf(vA.y, r1, aA[s]);  aB[s] = fmaf(vB.y, r1, aB[s]);
                    aA[s] = fmaf(vA.z, r2, aA[s]);  aB[s] = fmaf(vB.z, r2, aB[s]);
                    aA[s] = fmaf(vA.w, r3, aA[s]);  aB[s] = fmaf(vB.w, r3, aB[s]);
                }
            }
#pragma unroll
            for (int s = 0; s < SB; s++)
                *(float2*)&Gx[kh][s][g0] = make_float2(aA[s], aB[s]);
        } else {
            if (t > 0) {
                float p = 0.0f;
#pragma unroll
                for (int i = 0; i < 8; i++) p = fmaf(wn[i], hbuf[lw][nk * 8 + i], p);
                p += __shfl_xor(p, 1);
                p += __shfl_xor(p, 2);
                p += __shfl_xor(p, 4);
                if (nk == 0) gout[(size_t)(t - 1) * 8] = p + nbias;
            }
            float hv[SB];
#pragma unroll
            for (int s = 0; s < SB; s++) hv[s] = hbuf[s][hol];
            float aA[SB], aB[SB];
#pragma unroll
            for (int s = 0; s < SB; s++) { aA[s] = 0.0f; aB[s] = 0.0f; }
#pragma unroll
            for (int k4 = 0; k4 < 8; k4++) {
                const float4 vA = wA[k4], vB = wB[k4];
#pragma unroll
                for (int s = 0; s < SB; s++) {
                    const float r0 = rdl(hv[s], 4 * k4 + 0);
                    const float r1 = rdl(hv[s], 4 * k4 + 1);
                    const float r2 = rdl(hv[s], 4 * k4 + 2);
                    const float r3 = rdl(hv[s], 4 * k4 + 3);
                    aA[s] = fmaf(vA.x, r0, aA[s]);  aB[s] = fmaf(vB.x, r0, aB[s]);
                    aA[s] = fmaf(vA.y, r1, aA[s]);  aB[s] = fmaf(vB.y, r1, aB[s]);
                    aA[s] = fmaf(vA.z, r2, aA[s]);  aB[s] = fmaf(vB.z, r2, aB[s]);
                    aA[s] = fmaf(vA.w, r3, aA[s]);  aB[s] = fmaf(vB.w, r3, aB[s]);
                }
            }
#pragma unroll
            for (int s = 0; s < SB; s++)
                *(float2*)&Gh[kh][s][g0] = make_float2(aA[s], aB[s]);
        }
        __syncthreads();

        if (!isx) {
            const float i_p = Gx[0][lw][lane]       + Gx[1][lw][lane]
                            + Gh[0][lw][lane]       + Gh[1][lw][lane];
            const float f_p = Gx[0][lw][64 + lane]  + Gx[1][lw][64 + lane]
                            + Gh[0][lw][64 + lane]  + Gh[1][lw][64 + lane];
            const float g_p = Gx[0][lw][128 + lane] + Gx[1][lw][128 + lane]
                            + Gh[0][lw][128 + lane] + Gh[1][lw][128 + lane];
            const float o_p = Gx[0][lw][192 + lane] + Gx[1][lw][192 + lane]
                            + Gh[0][lw][192 + lane] + Gh[1][lw][192 + lane];
            cst = sigf(f_p) * cst + sigf(i_p) * tanhf(g_p);
            const float h = sigf(o_p) * tanhf(cst);
            hbuf[lw][lane] = h;
        } else if (t + 1 < TLEN) {
#pragma unroll
            for (int s = 0; s < SB; s++) xa[s] = xna[s];
        }
        __syncthreads();
    }

    if (!isx) {
        float p = 0.0f;
#pragma unroll
        for (int i = 0; i < 8; i++) p = fmaf(wn[i], hbuf[lw][nk * 8 + i], p);
        p += __shfl_xor(p, 1);
        p += __shfl_xor(p, 2);
        p += __shfl_xor(p, 4);
        if (nk == 0) gout[(size_t)(TLEN - 1) * 8] = p + nbias;
    }
}

// ---------------------------------------------------------------------------
extern "C" void kernel_launch(void* const* d_in, const int* in_sizes, int n_in,
                              void* d_out, int out_size, void* d_ws, size_t ws_size,
                              hipStream_t stream) {
    const float* x      = (const float*)d_in[0];  // (64,78,128,80)
    const float* w_ih_t = (const float*)d_in[1];  // (256,80)
    const float* w_hh_t = (const float*)d_in[2];  // (256,64)
    const float* b_ih_t = (const float*)d_in[3];  // (256)
    const float* b_hh_t = (const float*)d_in[4];  // (256)
    const float* w_ih_n = (const float*)d_in[5];  // (8,64)
    const float* w_hh_n = (const float*)d_in[6];  // (8,2)
    const float* b_ih_n = (const float*)d_in[7];  // (8)
    const float* b_hh_n = (const float*)d_in[8];  // (8)
    float* out = (float*)d_out;                   // (64,128,156)

    float* gxn = (float*)d_ws;                      // 20.4 MB
    float* gx  = (float*)((char*)d_ws + GXN_BYTES); // 654 MB

    if (ws_size >= WS_NEED) {
        gx_gemm2<<<NROWS / GR, 256, 0, stream>>>(x, w_ih_t, b_ih_t, b_hh_t, gx);
        rec_h2<<<RECBLK, 256, 0, stream>>>(gx, w_hh_t, w_ih_n, b_ih_n, b_hh_n, gxn);
    } else {
        time_lstm_fused_fb<<<NSEQ / SB, 512, 0, stream>>>(
            x, w_ih_t, w_hh_t, b_ih_t, b_hh_t, w_ih_n, b_ih_n, b_hh_n, gxn);
    }
    note_scan_kernel<<<NBT / 64, 64, 0, stream>>>(gxn, w_hh_n, out);
}